// Round 1
// 852.646 us; speedup vs baseline: 1.0038x; 1.0038x over previous
//
#include <hip/hip_runtime.h>

typedef unsigned int uint;
typedef unsigned short ushort;
typedef __bf16 v8b __attribute__((ext_vector_type(8)));
typedef float v4f __attribute__((ext_vector_type(4)));

#define NN 100000
#define EE 3200000
#define DD 128
#define NCH ((NN + 1023) / 1024)  // 98 scan chunks
#define NSLICE 8
#define SLICE_SZ (NN / NSLICE)  // 12500, exact

// ---- all scratch static: zero dependence on ws_size ----
__device__ __attribute__((aligned(256))) int g_deg[NN];
__device__ __attribute__((aligned(256))) int g_cursor[NN];
__device__ __attribute__((aligned(256))) int g_offs[NN + 1];
__device__ __attribute__((aligned(256))) int g_csum[NCH + 1];
__device__ __attribute__((aligned(256))) int g_flag[2];  // [0]=edge is64, [1]=float is fp32
__device__ __attribute__((aligned(256))) int g_bcnt[NSLICE];  // bucket fill counts
__device__ __attribute__((aligned(256))) int g_csr[EE];
// bucketed packed edges: (local_dst<<17)|src, bucket b at [b*EE, b*EE+bcnt[b])
__device__ __attribute__((aligned(256))) uint g_pairs[(size_t)NSLICE * EE];
// bf16 hi/lo split representations (hi also serves as the gather array)
__device__ __attribute__((aligned(256))) ushort g_emb_h[(size_t)NN * DD];
__device__ __attribute__((aligned(256))) ushort g_emb_l[(size_t)NN * DD];
__device__ __attribute__((aligned(256))) ushort g_agg_h[(size_t)NN * DD];
__device__ __attribute__((aligned(256))) ushort g_agg_l[(size_t)NN * DD];
__device__ __attribute__((aligned(256))) ushort g_hh[(size_t)NN * DD];
__device__ __attribute__((aligned(256))) ushort g_hl[(size_t)NN * DD];
__device__ __attribute__((aligned(256))) ushort g_w_h[4][DD * DD];  // Wl0,Wr0,Wl1,Wr1
__device__ __attribute__((aligned(256))) ushort g_w_l[4][DD * DD];
__device__ __attribute__((aligned(256))) float g_biasf[2][DD];  // b0,b1

__device__ __forceinline__ float blo(uint u) { return __uint_as_float(u << 16); }
__device__ __forceinline__ float bhi(uint u) { return __uint_as_float(u & 0xffff0000u); }
__device__ __forceinline__ ushort f2b(float f) {
  uint u = __float_as_uint(f);
  u += 0x7fffu + ((u >> 16) & 1u);  // RNE
  return (ushort)(u >> 16);
}
__device__ __forceinline__ float b2f(ushort s) { return __uint_as_float(((uint)s) << 16); }

// ---- dtype detection -----------------------------------------------------
__global__ void k_detect_ei(const int* __restrict__ ei) {
  __shared__ int any;
  if (threadIdx.x == 0) any = 0;
  __syncthreads();
  int v = 0;
  for (int i = threadIdx.x; i < 2048; i += 256) v |= ei[2 * i + 1];
  if (v) atomicOr(&any, 1);
  __syncthreads();
  if (threadIdx.x == 0) g_flag[0] = (any == 0) ? 1 : 0;  // 1 => int64
}

__global__ void k_detect_f(const ushort* __restrict__ u) {
  __shared__ int bad;
  if (threadIdx.x == 0) bad = 0;
  __syncthreads();
  int b = 0;
  for (int i = threadIdx.x; i < 2048; i += 256) {
    int e = (u[2 * i] >> 7) & 0xff;
    if (e < 0x40 || e > 0x7f) b = 1;
  }
  if (b) atomicOr(&bad, 1);
  __syncthreads();
  if (threadIdx.x == 0) g_flag[1] = bad;  // 1 => fp32
}

// ---- split fp32 (or bf16) tensor into bf16 hi + lo residual -------------
__global__ void k_split(const void* __restrict__ src, ushort* __restrict__ dh,
                        ushort* __restrict__ dl, int n) {
  int i = (blockIdx.x * blockDim.x + threadIdx.x) * 4;
  if (i >= n) return;
  float f[4];
  if (g_flag[1]) {
    float4 v = *(const float4*)((const float*)src + i);
    f[0] = v.x; f[1] = v.y; f[2] = v.z; f[3] = v.w;
  } else {
    ushort4 s = *(const ushort4*)((const ushort*)src + i);
    f[0] = b2f(s.x); f[1] = b2f(s.y); f[2] = b2f(s.z); f[3] = b2f(s.w);
  }
  ushort4 h, l;
  ushort* hp = &h.x;
  ushort* lp = &l.x;
#pragma unroll
  for (int k = 0; k < 4; k++) {
    ushort hi = f2b(f[k]);
    hp[k] = hi;
    lp[k] = f2b(f[k] - b2f(hi));
  }
  *(ushort4*)(dh + i) = h;
  *(ushort4*)(dl + i) = l;
}

__global__ void k_cvtb(const void* __restrict__ src, float* __restrict__ dst, int n) {
  int i = blockIdx.x * blockDim.x + threadIdx.x;
  if (i >= n) return;
  dst[i] = g_flag[1] ? ((const float*)src)[i] : b2f(((const ushort*)src)[i]);
}

__device__ __forceinline__ int ld_src(const int* __restrict__ ei, int is64, int e) {
  int v = is64 ? ei[2 * e] : ei[e];
  return ((uint)v < (uint)NN) ? v : 0;
}
__device__ __forceinline__ int ld_dst(const int* __restrict__ ei, int is64, int e) {
  int v = is64 ? ei[2 * (EE + e)] : ei[EE + e];
  return ((uint)v < (uint)NN) ? v : 0;
}

// ---------------- CSR build ----------------

__global__ void k_zero() {
  int i = blockIdx.x * blockDim.x + threadIdx.x;
  if (i < NN) g_deg[i] = 0;
  if (i < NSLICE) g_bcnt[i] = 0;
}

// Single pass over the edge stream: degree histogram + 8-way dst-slice
// bucketing. Pack (local_dst<<17)|src into one u32 (local_dst<12500 fits
// 14b, src<131072 fits 17b). Per-block LDS counters -> one global
// atomicAdd per bucket per block -> coalesced appends. This replaces the
// old k_deg pass AND the 8x full-stream re-scan inside k_scatter.
__global__ void k_degbucket(const int* __restrict__ ei) {
  int is64 = g_flag[0];
  __shared__ int s_cnt[NSLICE], s_base[NSLICE];
  if (threadIdx.x < NSLICE) s_cnt[threadIdx.x] = 0;
  __syncthreads();
  int base = blockIdx.x * 1024 + threadIdx.x;
  int b[4], idx[4];
  uint pk[4];
#pragma unroll
  for (int k = 0; k < 4; k++) {
    int e = base + k * 256;
    if (e < EE) {
      int d = ld_dst(ei, is64, e);
      int s = ld_src(ei, is64, e);
      atomicAdd(&g_deg[d], 1);
      int bb = d / SLICE_SZ;  // 0..7
      b[k] = bb;
      pk[k] = ((uint)(d - bb * SLICE_SZ) << 17) | (uint)s;
      idx[k] = atomicAdd(&s_cnt[bb], 1);
    } else {
      b[k] = -1;
      pk[k] = 0;
      idx[k] = 0;
    }
  }
  __syncthreads();
  if (threadIdx.x < NSLICE)
    s_base[threadIdx.x] = atomicAdd(&g_bcnt[threadIdx.x], s_cnt[threadIdx.x]);
  __syncthreads();
#pragma unroll
  for (int k = 0; k < 4; k++) {
    if (b[k] >= 0) {
      g_pairs[(size_t)b[k] * EE + (size_t)(s_base[b[k]] + idx[k])] = pk[k];
    }
  }
}

__global__ void k_scan_a() {
  __shared__ int sd[256];
  int t = threadIdx.x;
  int base = blockIdx.x * 1024 + t * 4;
  int s = 0;
#pragma unroll
  for (int k = 0; k < 4; k++) {
    int i = base + k;
    if (i < NN) s += g_deg[i];
  }
  sd[t] = s;
  __syncthreads();
  for (int off = 128; off > 0; off >>= 1) {
    if (t < off) sd[t] += sd[t + off];
    __syncthreads();
  }
  if (t == 0) g_csum[blockIdx.x] = sd[0];
}

__global__ void k_scan_b() {
  if (threadIdx.x == 0 && blockIdx.x == 0) {
    int run = 0;
    for (int i = 0; i < NCH; i++) {
      int v = g_csum[i];
      g_csum[i] = run;
      run += v;
    }
    g_offs[NN] = run;  // == EE
  }
}

__global__ void k_scan_c() {
  __shared__ int sd[256];
  int t = threadIdx.x;
  int base = blockIdx.x * 1024 + t * 4;
  int v[4];
  int s = 0;
#pragma unroll
  for (int k = 0; k < 4; k++) {
    int i = base + k;
    v[k] = (i < NN) ? g_deg[i] : 0;
    s += v[k];
  }
  sd[t] = s;
  __syncthreads();
  for (int off = 1; off < 256; off <<= 1) {
    int x = (t >= off) ? sd[t - off] : 0;
    __syncthreads();
    sd[t] += x;
    __syncthreads();
  }
  int excl = sd[t] - s + g_csum[blockIdx.x];
#pragma unroll
  for (int k = 0; k < 4; k++) {
    int i = base + k;
    if (i < NN) {
      g_offs[i] = excl;
      g_cursor[i] = excl;
      excl += v[k];
    }
  }
}

// Scatter from compact per-slice buckets. Each block owns one slice
// (slice = blockIdx&7), reads only that slice's bucket (~1.6 MB,
// coalesced grid-stride) and places srcs via the per-dst cursor atomic.
// Per-slice working set (pairs 1.6MB + csr 1.6MB + cursors 50KB) fits L2,
// so csr lines fill completely before writeback.
__global__ void k_scatter2() {
  int slice = blockIdx.x & (NSLICE - 1);
  int n = g_bcnt[slice];
  int lo = slice * SLICE_SZ;
  const uint* pr = g_pairs + (size_t)slice * EE;
  int stride = (gridDim.x >> 3) * 256;
  for (int e = (blockIdx.x >> 3) * 256 + threadIdx.x; e < n; e += stride) {
    uint v = pr[e];
    int d = lo + (int)(v >> 17);
    int p = atomicAdd(&g_cursor[d], 1);
    if ((uint)p < (uint)EE) g_csr[p] = (int)(v & 0x1FFFFu);
  }
}

// ------- mean aggregation: bf16 gather, fp32 accum, hi/lo bf16 out -------
// One wave per node; lane holds cols 2l,2l+1 (one uint = 2 bf16).
__global__ void k_agg(const ushort* __restrict__ x) {
  int lane = threadIdx.x & 63;
  int node = (blockIdx.x * blockDim.x + threadIdx.x) >> 6;
  int beg = g_offs[node], end = g_offs[node + 1];
  float a0 = 0.f, a1 = 0.f;
  int col = lane * 2;
  for (int c = beg; c < end; c += 64) {
    int cnt = end - c;
    if (cnt > 64) cnt = 64;
    int my = g_csr[c + (lane < cnt ? lane : cnt - 1)];
    if ((uint)my >= (uint)NN) my = 0;
    int cnt4 = cnt & ~3;
    int j = 0;
    for (; j < cnt4; j += 4) {
      int s0 = __shfl(my, j), s1 = __shfl(my, j + 1);
      int s2 = __shfl(my, j + 2), s3 = __shfl(my, j + 3);
      uint r0 = *(const uint*)(x + (size_t)s0 * DD + col);
      uint r1 = *(const uint*)(x + (size_t)s1 * DD + col);
      uint r2 = *(const uint*)(x + (size_t)s2 * DD + col);
      uint r3 = *(const uint*)(x + (size_t)s3 * DD + col);
      a0 += blo(r0) + blo(r1) + blo(r2) + blo(r3);
      a1 += bhi(r0) + bhi(r1) + bhi(r2) + bhi(r3);
    }
    for (; j < cnt; ++j) {
      int s = __shfl(my, j);
      uint r = *(const uint*)(x + (size_t)s * DD + col);
      a0 += blo(r);
      a1 += bhi(r);
    }
  }
  int deg = end - beg;
  float inv = deg > 0 ? 1.0f / (float)deg : 0.f;
  a0 *= inv;
  a1 *= inv;
  ushort h0 = f2b(a0), h1 = f2b(a1);
  ushort l0 = f2b(a0 - b2f(h0)), l1 = f2b(a1 - b2f(h1));
  size_t o = (size_t)node * DD + col;
  *(uint*)(g_agg_h + o) = (uint)h0 | ((uint)h1 << 16);
  *(uint*)(g_agg_l + o) = (uint)l0 | ((uint)l1 << 16);
}

// ------- MFMA linear, bf16x3: out = act(A1@Wl^T + b + A2@Wr^T) -----------
// (ah+al)(bh+bl) ~= ah*bh + ah*bl + al*bh  (error ~2^-16 rel, fp32 accum)
// One wave = 16 rows x 128 cols, mfma_f32_16x16x32_bf16.
// A frag: row=lane&15, k=(lane>>4)*8+j.  B frag: W row n=lane&15, same k.
// C/D: col=lane&15, row=(lane>>4)*4+reg.   (layouts verified: r4===r5 bitwise)
// MODE 0: bias+ReLU -> h hi/lo bf16.  MODE 1: bias+L2-normalize -> fp32 out.

template <int MODE>
__global__ __launch_bounds__(128) void k_lin(
    const ushort* __restrict__ A1h, const ushort* __restrict__ A1l,
    const ushort* __restrict__ A2h, const ushort* __restrict__ A2l,
    const ushort* __restrict__ Wlh, const ushort* __restrict__ Wll,
    const ushort* __restrict__ Wrh, const ushort* __restrict__ Wrl,
    const float* __restrict__ bias, void* out0, ushort* __restrict__ outlo) {
  int lane = threadIdx.x & 63;
  int wid = threadIdx.x >> 6;
  int m = lane & 15, q = lane >> 4;
  int row0 = (blockIdx.x * 2 + wid) * 16;
  size_t aoff = (size_t)(row0 + m) * DD + q * 8;
  v8b a1h[4], a1l[4], a2h[4], a2l[4];
#pragma unroll
  for (int ks = 0; ks < 4; ks++) {
    a1h[ks] = *(const v8b*)(A1h + aoff + ks * 32);
    a1l[ks] = *(const v8b*)(A1l + aoff + ks * 32);
    a2h[ks] = *(const v8b*)(A2h + aoff + ks * 32);
    a2l[ks] = *(const v8b*)(A2l + aoff + ks * 32);
  }
  v4f acc[8];
#pragma unroll
  for (int nt = 0; nt < 8; nt++) {
    v4f c = {0.f, 0.f, 0.f, 0.f};
    size_t boff = (size_t)(nt * 16 + m) * DD + q * 8;
#pragma unroll
    for (int ks = 0; ks < 4; ks++) {
      v8b blh = *(const v8b*)(Wlh + boff + ks * 32);
      v8b bll = *(const v8b*)(Wll + boff + ks * 32);
      v8b brh = *(const v8b*)(Wrh + boff + ks * 32);
      v8b brl = *(const v8b*)(Wrl + boff + ks * 32);
      c = __builtin_amdgcn_mfma_f32_16x16x32_bf16(a1h[ks], blh, c, 0, 0, 0);
      c = __builtin_amdgcn_mfma_f32_16x16x32_bf16(a1h[ks], bll, c, 0, 0, 0);
      c = __builtin_amdgcn_mfma_f32_16x16x32_bf16(a1l[ks], blh, c, 0, 0, 0);
      c = __builtin_amdgcn_mfma_f32_16x16x32_bf16(a2h[ks], brh, c, 0, 0, 0);
      c = __builtin_amdgcn_mfma_f32_16x16x32_bf16(a2h[ks], brl, c, 0, 0, 0);
      c = __builtin_amdgcn_mfma_f32_16x16x32_bf16(a2l[ks], brh, c, 0, 0, 0);
    }
    float bv = bias[nt * 16 + m];
#pragma unroll
    for (int r = 0; r < 4; r++) c[r] += bv;
    acc[nt] = c;
  }
  if (MODE == 0) {
    ushort* oh = (ushort*)out0;
#pragma unroll
    for (int nt = 0; nt < 8; nt++) {
#pragma unroll
      for (int r = 0; r < 4; r++) {
        float v = acc[nt][r];
        v = v > 0.f ? v : 0.f;
        ushort hi = f2b(v);
        ushort lo = f2b(v - b2f(hi));
        size_t o = (size_t)(row0 + q * 4 + r) * DD + nt * 16 + m;
        oh[o] = hi;
        outlo[o] = lo;
      }
    }
  } else {
    float* of = (float*)out0;
#pragma unroll
    for (int r = 0; r < 4; r++) {
      float p = 0.f;
#pragma unroll
      for (int nt = 0; nt < 8; nt++) p += acc[nt][r] * acc[nt][r];
      p += __shfl_xor(p, 1);
      p += __shfl_xor(p, 2);
      p += __shfl_xor(p, 4);
      p += __shfl_xor(p, 8);
      float inv = (p > 0.f) ? 1.0f / fmaxf(sqrtf(p), 1e-12f) : 0.f;
#pragma unroll
      for (int nt = 0; nt < 8; nt++)
        of[(size_t)(row0 + q * 4 + r) * DD + nt * 16 + m] = acc[nt][r] * inv;
    }
  }
}

// ---------------- launch ----------------

extern "C" void kernel_launch(void* const* d_in, const int* in_sizes, int n_in,
                              void* d_out, int out_size, void* d_ws, size_t ws_size,
                              hipStream_t stream) {
  const int* ei = (const int*)d_in[0];
  (void)in_sizes; (void)n_in; (void)out_size; (void)d_ws; (void)ws_size;

  ushort* wh;  hipGetSymbolAddress((void**)&wh, HIP_SYMBOL(g_w_h));
  ushort* wl;  hipGetSymbolAddress((void**)&wl, HIP_SYMBOL(g_w_l));
  ushort* wl0h = wh, *wr0h = wh + DD * DD, *wl1h = wh + 2 * DD * DD, *wr1h = wh + 3 * DD * DD;
  ushort* wl0l = wl, *wr0l = wl + DD * DD, *wl1l = wl + 2 * DD * DD, *wr1l = wl + 3 * DD * DD;
  float* bf;   hipGetSymbolAddress((void**)&bf, HIP_SYMBOL(g_biasf));
  float* b0 = bf, *b1 = bf + DD;
  ushort* eh;  hipGetSymbolAddress((void**)&eh, HIP_SYMBOL(g_emb_h));
  ushort* el;  hipGetSymbolAddress((void**)&el, HIP_SYMBOL(g_emb_l));
  ushort* ah;  hipGetSymbolAddress((void**)&ah, HIP_SYMBOL(g_agg_h));
  ushort* al;  hipGetSymbolAddress((void**)&al, HIP_SYMBOL(g_agg_l));
  ushort* hh;  hipGetSymbolAddress((void**)&hh, HIP_SYMBOL(g_hh));
  ushort* hl;  hipGetSymbolAddress((void**)&hl, HIP_SYMBOL(g_hl));

  k_detect_ei<<<1, 256, 0, stream>>>(ei);
  k_detect_f<<<1, 256, 0, stream>>>((const ushort*)d_in[1]);

  k_split<<<(NN * DD / 4 + 255) / 256, 256, 0, stream>>>(d_in[1], eh, el, NN * DD);
  k_split<<<(DD * DD / 4 + 255) / 256, 256, 0, stream>>>(d_in[2], wl0h, wl0l, DD * DD);
  k_split<<<(DD * DD / 4 + 255) / 256, 256, 0, stream>>>(d_in[4], wr0h, wr0l, DD * DD);
  k_split<<<(DD * DD / 4 + 255) / 256, 256, 0, stream>>>(d_in[5], wl1h, wl1l, DD * DD);
  k_split<<<(DD * DD / 4 + 255) / 256, 256, 0, stream>>>(d_in[7], wr1h, wr1l, DD * DD);
  k_cvtb<<<1, 128, 0, stream>>>(d_in[3], b0, DD);
  k_cvtb<<<1, 128, 0, stream>>>(d_in[6], b1, DD);

  k_zero<<<(NN + 255) / 256, 256, 0, stream>>>();
  k_degbucket<<<(EE + 1023) / 1024, 256, 0, stream>>>(ei);
  k_scan_a<<<NCH, 256, 0, stream>>>();
  k_scan_b<<<1, 64, 0, stream>>>();
  k_scan_c<<<NCH, 256, 0, stream>>>();
  k_scatter2<<<NSLICE * 512, 256, 0, stream>>>();

  k_agg<<<NN / 4, 256, 0, stream>>>(eh);
  k_lin<0><<<NN / 32, 128, 0, stream>>>(ah, al, eh, el, wl0h, wl0l, wr0h, wr0l, b0, hh, hl);
  k_agg<<<NN / 4, 256, 0, stream>>>(hh);
  k_lin<1><<<NN / 32, 128, 0, stream>>>(ah, al, hh, hl, wl1h, wl1l, wr1h, wr1l, b1, d_out, nullptr);
}

// Round 2
// 652.764 us; speedup vs baseline: 1.3112x; 1.3062x over previous
//
#include <hip/hip_runtime.h>

typedef unsigned int uint;
typedef unsigned short ushort;
typedef __bf16 v8b __attribute__((ext_vector_type(8)));
typedef float v4f __attribute__((ext_vector_type(4)));

#define NN 100000
#define EE 3200000
#define DD 128

// counting-sort CSR build: 391 buckets x 256 nodes
#define BSH 8
#define BSZ 256                    // nodes per bucket (1<<BSH)
#define NB ((NN + BSZ - 1) / BSZ)  // 391
#define CAP 16384                  // per-bucket capacity (avg fill ~8184)
#define EPB 8192                   // edges per block in k_bucket
#define NBLK1 ((EE + EPB - 1) / EPB)  // 391

// ---- all scratch static: zero dependence on ws_size ----
__device__ __attribute__((aligned(256))) int g_offs[NN + 1];
__device__ __attribute__((aligned(256))) int g_flag[2];    // [0]=edge is64, [1]=float is fp32
__device__ __attribute__((aligned(256))) int g_bcnt2[NB];  // bucket fill counts
__device__ __attribute__((aligned(256))) int g_bbase[NB];  // bucket base offsets (excl scan)
__device__ __attribute__((aligned(256))) int g_csr[EE];
// bucketed packed edges: (local_dst<<17)|src, bucket b at [b*CAP, b*CAP+cnt)
__device__ __attribute__((aligned(256))) uint g_pairs2[(size_t)NB * CAP];
// bf16 hi/lo split representations (hi also serves as the gather array)
__device__ __attribute__((aligned(256))) ushort g_emb_h[(size_t)NN * DD];
__device__ __attribute__((aligned(256))) ushort g_emb_l[(size_t)NN * DD];
__device__ __attribute__((aligned(256))) ushort g_agg_h[(size_t)NN * DD];
__device__ __attribute__((aligned(256))) ushort g_agg_l[(size_t)NN * DD];
__device__ __attribute__((aligned(256))) ushort g_hh[(size_t)NN * DD];
__device__ __attribute__((aligned(256))) ushort g_hl[(size_t)NN * DD];
__device__ __attribute__((aligned(256))) ushort g_w_h[4][DD * DD];  // Wl0,Wr0,Wl1,Wr1
__device__ __attribute__((aligned(256))) ushort g_w_l[4][DD * DD];
__device__ __attribute__((aligned(256))) float g_biasf[2][DD];  // b0,b1

__device__ __forceinline__ float blo(uint u) { return __uint_as_float(u << 16); }
__device__ __forceinline__ float bhi(uint u) { return __uint_as_float(u & 0xffff0000u); }
__device__ __forceinline__ ushort f2b(float f) {
  uint u = __float_as_uint(f);
  u += 0x7fffu + ((u >> 16) & 1u);  // RNE
  return (ushort)(u >> 16);
}
__device__ __forceinline__ float b2f(ushort s) { return __uint_as_float(((uint)s) << 16); }

// ---- dtype detection -----------------------------------------------------
__global__ void k_detect_ei(const int* __restrict__ ei) {
  __shared__ int any;
  if (threadIdx.x == 0) any = 0;
  __syncthreads();
  int v = 0;
  for (int i = threadIdx.x; i < 2048; i += 256) v |= ei[2 * i + 1];
  if (v) atomicOr(&any, 1);
  __syncthreads();
  if (threadIdx.x == 0) g_flag[0] = (any == 0) ? 1 : 0;  // 1 => int64
}

__global__ void k_detect_f(const ushort* __restrict__ u) {
  __shared__ int bad;
  if (threadIdx.x == 0) bad = 0;
  __syncthreads();
  int b = 0;
  for (int i = threadIdx.x; i < 2048; i += 256) {
    int e = (u[2 * i] >> 7) & 0xff;
    if (e < 0x40 || e > 0x7f) b = 1;
  }
  if (b) atomicOr(&bad, 1);
  __syncthreads();
  if (threadIdx.x == 0) g_flag[1] = bad;  // 1 => fp32
}

// ---- split fp32 (or bf16) tensor into bf16 hi + lo residual -------------
__global__ void k_split(const void* __restrict__ src, ushort* __restrict__ dh,
                        ushort* __restrict__ dl, int n) {
  int i = (blockIdx.x * blockDim.x + threadIdx.x) * 4;
  if (i >= n) return;
  float f[4];
  if (g_flag[1]) {
    float4 v = *(const float4*)((const float*)src + i);
    f[0] = v.x; f[1] = v.y; f[2] = v.z; f[3] = v.w;
  } else {
    ushort4 s = *(const ushort4*)((const ushort*)src + i);
    f[0] = b2f(s.x); f[1] = b2f(s.y); f[2] = b2f(s.z); f[3] = b2f(s.w);
  }
  ushort4 h, l;
  ushort* hp = &h.x;
  ushort* lp = &l.x;
#pragma unroll
  for (int k = 0; k < 4; k++) {
    ushort hi = f2b(f[k]);
    hp[k] = hi;
    lp[k] = f2b(f[k] - b2f(hi));
  }
  *(ushort4*)(dh + i) = h;
  *(ushort4*)(dl + i) = l;
}

__global__ void k_cvtb(const void* __restrict__ src, float* __restrict__ dst, int n) {
  int i = blockIdx.x * blockDim.x + threadIdx.x;
  if (i >= n) return;
  dst[i] = g_flag[1] ? ((const float*)src)[i] : b2f(((const ushort*)src)[i]);
}

__device__ __forceinline__ int ld_src(const int* __restrict__ ei, int is64, int e) {
  int v = is64 ? ei[2 * e] : ei[e];
  return ((uint)v < (uint)NN) ? v : 0;
}
__device__ __forceinline__ int ld_dst(const int* __restrict__ ei, int is64, int e) {
  int v = is64 ? ei[2 * (EE + e)] : ei[EE + e];
  return ((uint)v < (uint)NN) ? v : 0;
}

// ---------------- CSR build (counting sort, no per-edge global atomics) ----

__global__ void k_zero2() {
  int i = threadIdx.x;
  if (i < NB) g_bcnt2[i] = 0;
}

// One pass over the edge stream. Per-block LDS staging of packed edges +
// 391-counter LDS histogram; ONE global atomicAdd per bucket per block
// (153K total, vs 3.2M per-edge atomics before); compact appends into
// fixed-capacity bucket regions. pack = (local_dst<<17)|src
// (local<256 = 8b, src<131072 = 17b).
__global__ __launch_bounds__(256) void k_bucket(const int* __restrict__ ei) {
  int is64 = g_flag[0];
  __shared__ uint s_pk[EPB];    // 32 KB
  __shared__ ushort s_bk[EPB];  // 16 KB
  __shared__ int s_cnt[NB];
  __shared__ int s_base[NB];
  for (int i = threadIdx.x; i < NB; i += 256) s_cnt[i] = 0;
  __syncthreads();
  int base = blockIdx.x * EPB;
  // phase A: load, pack, count
#pragma unroll
  for (int i = 0; i < EPB / 256; i++) {
    int li = i * 256 + threadIdx.x;
    int e = base + li;
    uint pk = 0;
    int b = -1;
    if (e < EE) {
      int d = ld_dst(ei, is64, e);
      int s = ld_src(ei, is64, e);
      b = d >> BSH;
      pk = ((uint)(d & (BSZ - 1)) << 17) | (uint)s;
      atomicAdd(&s_cnt[b], 1);
    }
    s_pk[li] = pk;
    s_bk[li] = (ushort)b;  // 0xffff sentinel when invalid
  }
  __syncthreads();
  // reserve global bases: one atomic per non-empty bucket
  for (int i = threadIdx.x; i < NB; i += 256) {
    int c = s_cnt[i];
    s_base[i] = c ? atomicAdd(&g_bcnt2[i], c) : 0;
    s_cnt[i] = 0;  // reuse as cursor
  }
  __syncthreads();
  // phase B: append
#pragma unroll
  for (int i = 0; i < EPB / 256; i++) {
    int li = i * 256 + threadIdx.x;
    int b = s_bk[li];
    if (b != 0xffff) {
      int idx = s_base[b] + atomicAdd(&s_cnt[b], 1);
      if (idx < CAP) g_pairs2[(size_t)b * CAP + idx] = s_pk[li];
    }
  }
}

// exclusive scan of bucket counts -> bucket base offsets; total -> g_offs[NN]
__global__ void k_bscan() {
  __shared__ int sd[512];
  int t = threadIdx.x;
  int v = (t < NB) ? min(g_bcnt2[t], CAP) : 0;
  sd[t] = v;
  __syncthreads();
  for (int off = 1; off < 512; off <<= 1) {
    int x = (t >= off) ? sd[t - off] : 0;
    __syncthreads();
    sd[t] += x;
    __syncthreads();
  }
  if (t < NB) g_bbase[t] = sd[t] - v;
  if (t == 511) g_offs[NN] = sd[511];
}

// One block per bucket: LDS histogram of 256 local dsts, LDS scan, write
// g_offs for its 256 nodes (exclusive ownership - no atomics), then place
// srcs into g_csr via LDS cursors. Per-block working set ~64KB -> L2-local.
__global__ __launch_bounds__(256) void k_place() {
  int b = blockIdx.x;
  int n = min(g_bcnt2[b], CAP);
  int gbase = g_bbase[b];
  const uint* pr = g_pairs2 + (size_t)b * CAP;
  __shared__ int hist[BSZ];
  __shared__ int sd[BSZ];
  __shared__ int cur[BSZ];
  int t = threadIdx.x;
  hist[t] = 0;
  __syncthreads();
  for (int e = t; e < n; e += 256) atomicAdd(&hist[pr[e] >> 17], 1);
  __syncthreads();
  int v = hist[t];
  sd[t] = v;
  __syncthreads();
  for (int off = 1; off < BSZ; off <<= 1) {
    int x = (t >= off) ? sd[t - off] : 0;
    __syncthreads();
    sd[t] += x;
    __syncthreads();
  }
  int excl = sd[t] - v;
  int node = (b << BSH) + t;
  if (node < NN) g_offs[node] = gbase + excl;
  cur[t] = excl;
  __syncthreads();
  for (int e = t; e < n; e += 256) {
    uint pk = pr[e];
    int p = atomicAdd(&cur[pk >> 17], 1);
    g_csr[gbase + p] = (int)(pk & 0x1FFFFu);
  }
}

// ------- mean aggregation: bf16 gather, fp32 accum, hi/lo bf16 out -------
// One wave per node; lane holds cols 2l,2l+1 (one uint = 2 bf16).
__global__ void k_agg(const ushort* __restrict__ x) {
  int lane = threadIdx.x & 63;
  int node = (blockIdx.x * blockDim.x + threadIdx.x) >> 6;
  int beg = g_offs[node], end = g_offs[node + 1];
  float a0 = 0.f, a1 = 0.f;
  int col = lane * 2;
  for (int c = beg; c < end; c += 64) {
    int cnt = end - c;
    if (cnt > 64) cnt = 64;
    int my = g_csr[c + (lane < cnt ? lane : cnt - 1)];
    if ((uint)my >= (uint)NN) my = 0;
    int cnt4 = cnt & ~3;
    int j = 0;
    for (; j < cnt4; j += 4) {
      int s0 = __shfl(my, j), s1 = __shfl(my, j + 1);
      int s2 = __shfl(my, j + 2), s3 = __shfl(my, j + 3);
      uint r0 = *(const uint*)(x + (size_t)s0 * DD + col);
      uint r1 = *(const uint*)(x + (size_t)s1 * DD + col);
      uint r2 = *(const uint*)(x + (size_t)s2 * DD + col);
      uint r3 = *(const uint*)(x + (size_t)s3 * DD + col);
      a0 += blo(r0) + blo(r1) + blo(r2) + blo(r3);
      a1 += bhi(r0) + bhi(r1) + bhi(r2) + bhi(r3);
    }
    for (; j < cnt; ++j) {
      int s = __shfl(my, j);
      uint r = *(const uint*)(x + (size_t)s * DD + col);
      a0 += blo(r);
      a1 += bhi(r);
    }
  }
  int deg = end - beg;
  float inv = deg > 0 ? 1.0f / (float)deg : 0.f;
  a0 *= inv;
  a1 *= inv;
  ushort h0 = f2b(a0), h1 = f2b(a1);
  ushort l0 = f2b(a0 - b2f(h0)), l1 = f2b(a1 - b2f(h1));
  size_t o = (size_t)node * DD + col;
  *(uint*)(g_agg_h + o) = (uint)h0 | ((uint)h1 << 16);
  *(uint*)(g_agg_l + o) = (uint)l0 | ((uint)l1 << 16);
}

// ------- MFMA linear, bf16x3: out = act(A1@Wl^T + b + A2@Wr^T) -----------
// (ah+al)(bh+bl) ~= ah*bh + ah*bl + al*bh  (error ~2^-16 rel, fp32 accum)
// One wave = 16 rows x 128 cols, mfma_f32_16x16x32_bf16.
// A frag: row=lane&15, k=(lane>>4)*8+j.  B frag: W row n=lane&15, same k.
// C/D: col=lane&15, row=(lane>>4)*4+reg.   (layouts verified: r4===r5 bitwise)
// MODE 0: bias+ReLU -> h hi/lo bf16.  MODE 1: bias+L2-normalize -> fp32 out.

template <int MODE>
__global__ __launch_bounds__(128) void k_lin(
    const ushort* __restrict__ A1h, const ushort* __restrict__ A1l,
    const ushort* __restrict__ A2h, const ushort* __restrict__ A2l,
    const ushort* __restrict__ Wlh, const ushort* __restrict__ Wll,
    const ushort* __restrict__ Wrh, const ushort* __restrict__ Wrl,
    const float* __restrict__ bias, void* out0, ushort* __restrict__ outlo) {
  int lane = threadIdx.x & 63;
  int wid = threadIdx.x >> 6;
  int m = lane & 15, q = lane >> 4;
  int row0 = (blockIdx.x * 2 + wid) * 16;
  size_t aoff = (size_t)(row0 + m) * DD + q * 8;
  v8b a1h[4], a1l[4], a2h[4], a2l[4];
#pragma unroll
  for (int ks = 0; ks < 4; ks++) {
    a1h[ks] = *(const v8b*)(A1h + aoff + ks * 32);
    a1l[ks] = *(const v8b*)(A1l + aoff + ks * 32);
    a2h[ks] = *(const v8b*)(A2h + aoff + ks * 32);
    a2l[ks] = *(const v8b*)(A2l + aoff + ks * 32);
  }
  v4f acc[8];
#pragma unroll
  for (int nt = 0; nt < 8; nt++) {
    v4f c = {0.f, 0.f, 0.f, 0.f};
    size_t boff = (size_t)(nt * 16 + m) * DD + q * 8;
#pragma unroll
    for (int ks = 0; ks < 4; ks++) {
      v8b blh = *(const v8b*)(Wlh + boff + ks * 32);
      v8b bll = *(const v8b*)(Wll + boff + ks * 32);
      v8b brh = *(const v8b*)(Wrh + boff + ks * 32);
      v8b brl = *(const v8b*)(Wrl + boff + ks * 32);
      c = __builtin_amdgcn_mfma_f32_16x16x32_bf16(a1h[ks], blh, c, 0, 0, 0);
      c = __builtin_amdgcn_mfma_f32_16x16x32_bf16(a1h[ks], bll, c, 0, 0, 0);
      c = __builtin_amdgcn_mfma_f32_16x16x32_bf16(a1l[ks], blh, c, 0, 0, 0);
      c = __builtin_amdgcn_mfma_f32_16x16x32_bf16(a2h[ks], brh, c, 0, 0, 0);
      c = __builtin_amdgcn_mfma_f32_16x16x32_bf16(a2h[ks], brl, c, 0, 0, 0);
      c = __builtin_amdgcn_mfma_f32_16x16x32_bf16(a2l[ks], brh, c, 0, 0, 0);
    }
    float bv = bias[nt * 16 + m];
#pragma unroll
    for (int r = 0; r < 4; r++) c[r] += bv;
    acc[nt] = c;
  }
  if (MODE == 0) {
    ushort* oh = (ushort*)out0;
#pragma unroll
    for (int nt = 0; nt < 8; nt++) {
#pragma unroll
      for (int r = 0; r < 4; r++) {
        float v = acc[nt][r];
        v = v > 0.f ? v : 0.f;
        ushort hi = f2b(v);
        ushort lo = f2b(v - b2f(hi));
        size_t o = (size_t)(row0 + q * 4 + r) * DD + nt * 16 + m;
        oh[o] = hi;
        outlo[o] = lo;
      }
    }
  } else {
    float* of = (float*)out0;
#pragma unroll
    for (int r = 0; r < 4; r++) {
      float p = 0.f;
#pragma unroll
      for (int nt = 0; nt < 8; nt++) p += acc[nt][r] * acc[nt][r];
      p += __shfl_xor(p, 1);
      p += __shfl_xor(p, 2);
      p += __shfl_xor(p, 4);
      p += __shfl_xor(p, 8);
      float inv = (p > 0.f) ? 1.0f / fmaxf(sqrtf(p), 1e-12f) : 0.f;
#pragma unroll
      for (int nt = 0; nt < 8; nt++)
        of[(size_t)(row0 + q * 4 + r) * DD + nt * 16 + m] = acc[nt][r] * inv;
    }
  }
}

// ---------------- launch ----------------

extern "C" void kernel_launch(void* const* d_in, const int* in_sizes, int n_in,
                              void* d_out, int out_size, void* d_ws, size_t ws_size,
                              hipStream_t stream) {
  const int* ei = (const int*)d_in[0];
  (void)in_sizes; (void)n_in; (void)out_size; (void)d_ws; (void)ws_size;

  ushort* wh;  hipGetSymbolAddress((void**)&wh, HIP_SYMBOL(g_w_h));
  ushort* wl;  hipGetSymbolAddress((void**)&wl, HIP_SYMBOL(g_w_l));
  ushort* wl0h = wh, *wr0h = wh + DD * DD, *wl1h = wh + 2 * DD * DD, *wr1h = wh + 3 * DD * DD;
  ushort* wl0l = wl, *wr0l = wl + DD * DD, *wl1l = wl + 2 * DD * DD, *wr1l = wl + 3 * DD * DD;
  float* bf;   hipGetSymbolAddress((void**)&bf, HIP_SYMBOL(g_biasf));
  float* b0 = bf, *b1 = bf + DD;
  ushort* eh;  hipGetSymbolAddress((void**)&eh, HIP_SYMBOL(g_emb_h));
  ushort* el;  hipGetSymbolAddress((void**)&el, HIP_SYMBOL(g_emb_l));
  ushort* ah;  hipGetSymbolAddress((void**)&ah, HIP_SYMBOL(g_agg_h));
  ushort* al;  hipGetSymbolAddress((void**)&al, HIP_SYMBOL(g_agg_l));
  ushort* hh;  hipGetSymbolAddress((void**)&hh, HIP_SYMBOL(g_hh));
  ushort* hl;  hipGetSymbolAddress((void**)&hl, HIP_SYMBOL(g_hl));

  k_detect_ei<<<1, 256, 0, stream>>>(ei);
  k_detect_f<<<1, 256, 0, stream>>>((const ushort*)d_in[1]);

  k_split<<<(NN * DD / 4 + 255) / 256, 256, 0, stream>>>(d_in[1], eh, el, NN * DD);
  k_split<<<(DD * DD / 4 + 255) / 256, 256, 0, stream>>>(d_in[2], wl0h, wl0l, DD * DD);
  k_split<<<(DD * DD / 4 + 255) / 256, 256, 0, stream>>>(d_in[4], wr0h, wr0l, DD * DD);
  k_split<<<(DD * DD / 4 + 255) / 256, 256, 0, stream>>>(d_in[5], wl1h, wl1l, DD * DD);
  k_split<<<(DD * DD / 4 + 255) / 256, 256, 0, stream>>>(d_in[7], wr1h, wr1l, DD * DD);
  k_cvtb<<<1, 128, 0, stream>>>(d_in[3], b0, DD);
  k_cvtb<<<1, 128, 0, stream>>>(d_in[6], b1, DD);

  k_zero2<<<1, 512, 0, stream>>>();
  k_bucket<<<NBLK1, 256, 0, stream>>>(ei);
  k_bscan<<<1, 512, 0, stream>>>();
  k_place<<<NB, 256, 0, stream>>>();

  k_agg<<<NN / 4, 256, 0, stream>>>(eh);
  k_lin<0><<<NN / 32, 128, 0, stream>>>(ah, al, eh, el, wl0h, wl0l, wr0h, wr0l, b0, hh, hl);
  k_agg<<<NN / 4, 256, 0, stream>>>(hh);
  k_lin<1><<<NN / 32, 128, 0, stream>>>(ah, al, hh, hl, wl1h, wl1l, wr1h, wr1l, b1, d_out, nullptr);
}

// Round 3
// 600.823 us; speedup vs baseline: 1.4245x; 1.0864x over previous
//
#include <hip/hip_runtime.h>

typedef unsigned int uint;
typedef unsigned short ushort;
typedef __bf16 v8b __attribute__((ext_vector_type(8)));
typedef float v4f __attribute__((ext_vector_type(4)));

#define NN 100000
#define EE 3200000
#define DD 128

// counting-sort CSR build: 391 buckets x 256 nodes
#define BSH 8
#define BSZ 256                    // nodes per bucket (1<<BSH)
#define NB ((NN + BSZ - 1) / BSZ)  // 391
#define CAP 16384                  // per-bucket capacity (avg fill ~8184)
#define EPB 8192                   // edges per block in k_bucket
#define NBLK1 ((EE + EPB - 1) / EPB)  // 391

// k_lin: wave = 32 rows, block = 4 waves = 128 rows
#define LWAVES ((NN + 31) / 32)          // 3125
#define LGRID ((LWAVES + 3) / 4)         // 782

// ---- all scratch static: zero dependence on ws_size ----
__device__ __attribute__((aligned(256))) int g_offs[NN + 1];
__device__ __attribute__((aligned(256))) int g_flag[2];    // [0]=edge is64, [1]=float is fp32
__device__ __attribute__((aligned(256))) int g_bcnt2[NB];  // bucket fill counts
__device__ __attribute__((aligned(256))) int g_bbase[NB];  // bucket base offsets (excl scan)
__device__ __attribute__((aligned(256))) int g_csr[EE];
// bucketed packed edges: (local_dst<<17)|src, bucket b at [b*CAP, b*CAP+cnt)
__device__ __attribute__((aligned(256))) uint g_pairs2[(size_t)NB * CAP];
// bf16 hi/lo split representations (hi also serves as the gather array)
__device__ __attribute__((aligned(256))) ushort g_emb_h[(size_t)NN * DD];
__device__ __attribute__((aligned(256))) ushort g_emb_l[(size_t)NN * DD];
__device__ __attribute__((aligned(256))) ushort g_agg_h[(size_t)NN * DD];
__device__ __attribute__((aligned(256))) ushort g_agg_l[(size_t)NN * DD];
__device__ __attribute__((aligned(256))) ushort g_hh[(size_t)NN * DD];
__device__ __attribute__((aligned(256))) ushort g_hl[(size_t)NN * DD];
__device__ __attribute__((aligned(256))) ushort g_w_h[4][DD * DD];  // Wl0,Wr0,Wl1,Wr1
__device__ __attribute__((aligned(256))) ushort g_w_l[4][DD * DD];
__device__ __attribute__((aligned(256))) float g_biasf[2][DD];  // b0,b1

__device__ __forceinline__ float blo(uint u) { return __uint_as_float(u << 16); }
__device__ __forceinline__ float bhi(uint u) { return __uint_as_float(u & 0xffff0000u); }
__device__ __forceinline__ ushort f2b(float f) {
  uint u = __float_as_uint(f);
  u += 0x7fffu + ((u >> 16) & 1u);  // RNE
  return (ushort)(u >> 16);
}
__device__ __forceinline__ float b2f(ushort s) { return __uint_as_float(((uint)s) << 16); }

// ---- dtype detection -----------------------------------------------------
__global__ void k_detect_ei(const int* __restrict__ ei) {
  __shared__ int any;
  if (threadIdx.x == 0) any = 0;
  __syncthreads();
  int v = 0;
  for (int i = threadIdx.x; i < 2048; i += 256) v |= ei[2 * i + 1];
  if (v) atomicOr(&any, 1);
  __syncthreads();
  if (threadIdx.x == 0) g_flag[0] = (any == 0) ? 1 : 0;  // 1 => int64
}

__global__ void k_detect_f(const ushort* __restrict__ u) {
  __shared__ int bad;
  if (threadIdx.x == 0) bad = 0;
  __syncthreads();
  int b = 0;
  for (int i = threadIdx.x; i < 2048; i += 256) {
    int e = (u[2 * i] >> 7) & 0xff;
    if (e < 0x40 || e > 0x7f) b = 1;
  }
  if (b) atomicOr(&bad, 1);
  __syncthreads();
  if (threadIdx.x == 0) g_flag[1] = bad;  // 1 => fp32
}

// ---- split fp32 (or bf16) tensor into bf16 hi + lo residual -------------
__global__ void k_split(const void* __restrict__ src, ushort* __restrict__ dh,
                        ushort* __restrict__ dl, int n) {
  int i = (blockIdx.x * blockDim.x + threadIdx.x) * 4;
  if (i >= n) return;
  float f[4];
  if (g_flag[1]) {
    float4 v = *(const float4*)((const float*)src + i);
    f[0] = v.x; f[1] = v.y; f[2] = v.z; f[3] = v.w;
  } else {
    ushort4 s = *(const ushort4*)((const ushort*)src + i);
    f[0] = b2f(s.x); f[1] = b2f(s.y); f[2] = b2f(s.z); f[3] = b2f(s.w);
  }
  ushort4 h, l;
  ushort* hp = &h.x;
  ushort* lp = &l.x;
#pragma unroll
  for (int k = 0; k < 4; k++) {
    ushort hi = f2b(f[k]);
    hp[k] = hi;
    lp[k] = f2b(f[k] - b2f(hi));
  }
  *(ushort4*)(dh + i) = h;
  *(ushort4*)(dl + i) = l;
}

__global__ void k_cvtb(const void* __restrict__ src, float* __restrict__ dst, int n) {
  int i = blockIdx.x * blockDim.x + threadIdx.x;
  if (i >= n) return;
  dst[i] = g_flag[1] ? ((const float*)src)[i] : b2f(((const ushort*)src)[i]);
}

__device__ __forceinline__ int ld_src(const int* __restrict__ ei, int is64, int e) {
  int v = is64 ? ei[2 * e] : ei[e];
  return ((uint)v < (uint)NN) ? v : 0;
}
__device__ __forceinline__ int ld_dst(const int* __restrict__ ei, int is64, int e) {
  int v = is64 ? ei[2 * (EE + e)] : ei[EE + e];
  return ((uint)v < (uint)NN) ? v : 0;
}

// ---------------- CSR build (counting sort, no per-edge global atomics) ----

__global__ void k_zero2() {
  int i = threadIdx.x;
  if (i < NB) g_bcnt2[i] = 0;
}

// One pass over the edge stream. Per-block LDS staging of packed edges +
// 391-counter LDS histogram; ONE global atomicAdd per bucket per block
// (153K total); compact appends into fixed-capacity bucket regions.
// pack = (local_dst<<17)|src  (local<256 = 8b, src<131072 = 17b).
__global__ __launch_bounds__(256) void k_bucket(const int* __restrict__ ei) {
  int is64 = g_flag[0];
  __shared__ uint s_pk[EPB];    // 32 KB
  __shared__ ushort s_bk[EPB];  // 16 KB
  __shared__ int s_cnt[NB];
  __shared__ int s_base[NB];
  for (int i = threadIdx.x; i < NB; i += 256) s_cnt[i] = 0;
  __syncthreads();
  int base = blockIdx.x * EPB;
  // phase A: load, pack, count
#pragma unroll
  for (int i = 0; i < EPB / 256; i++) {
    int li = i * 256 + threadIdx.x;
    int e = base + li;
    uint pk = 0;
    int b = -1;
    if (e < EE) {
      int d = ld_dst(ei, is64, e);
      int s = ld_src(ei, is64, e);
      b = d >> BSH;
      pk = ((uint)(d & (BSZ - 1)) << 17) | (uint)s;
      atomicAdd(&s_cnt[b], 1);
    }
    s_pk[li] = pk;
    s_bk[li] = (ushort)b;  // 0xffff sentinel when invalid
  }
  __syncthreads();
  // reserve global bases: one atomic per non-empty bucket
  for (int i = threadIdx.x; i < NB; i += 256) {
    int c = s_cnt[i];
    s_base[i] = c ? atomicAdd(&g_bcnt2[i], c) : 0;
    s_cnt[i] = 0;  // reuse as cursor
  }
  __syncthreads();
  // phase B: append
#pragma unroll
  for (int i = 0; i < EPB / 256; i++) {
    int li = i * 256 + threadIdx.x;
    int b = s_bk[li];
    if (b != 0xffff) {
      int idx = s_base[b] + atomicAdd(&s_cnt[b], 1);
      if (idx < CAP) g_pairs2[(size_t)b * CAP + idx] = s_pk[li];
    }
  }
}

// exclusive scan of bucket counts -> bucket base offsets; total -> g_offs[NN]
__global__ void k_bscan() {
  __shared__ int sd[512];
  int t = threadIdx.x;
  int v = (t < NB) ? min(g_bcnt2[t], CAP) : 0;
  sd[t] = v;
  __syncthreads();
  for (int off = 1; off < 512; off <<= 1) {
    int x = (t >= off) ? sd[t - off] : 0;
    __syncthreads();
    sd[t] += x;
    __syncthreads();
  }
  if (t < NB) g_bbase[t] = sd[t] - v;
  if (t == 511) g_offs[NN] = sd[511];
}

// One block per bucket: LDS histogram of 256 local dsts, LDS scan, write
// g_offs for its 256 nodes (exclusive ownership - no atomics), then place
// srcs into g_csr via LDS cursors. Per-block working set ~64KB -> L2-local.
__global__ __launch_bounds__(256) void k_place() {
  int b = blockIdx.x;
  int n = min(g_bcnt2[b], CAP);
  int gbase = g_bbase[b];
  const uint* pr = g_pairs2 + (size_t)b * CAP;
  __shared__ int hist[BSZ];
  __shared__ int sd[BSZ];
  __shared__ int cur[BSZ];
  int t = threadIdx.x;
  hist[t] = 0;
  __syncthreads();
  for (int e = t; e < n; e += 256) atomicAdd(&hist[pr[e] >> 17], 1);
  __syncthreads();
  int v = hist[t];
  sd[t] = v;
  __syncthreads();
  for (int off = 1; off < BSZ; off <<= 1) {
    int x = (t >= off) ? sd[t - off] : 0;
    __syncthreads();
    sd[t] += x;
    __syncthreads();
  }
  int excl = sd[t] - v;
  int node = (b << BSH) + t;
  if (node < NN) g_offs[node] = gbase + excl;
  cur[t] = excl;
  __syncthreads();
  for (int e = t; e < n; e += 256) {
    uint pk = pr[e];
    int p = atomicAdd(&cur[pk >> 17], 1);
    g_csr[gbase + p] = (int)(pk & 0x1FFFFu);
  }
}

// ------- mean aggregation: bf16 gather, fp32 accum, hi/lo bf16 out -------
// One wave per node; lane holds cols 2l,2l+1 (one uint = 2 bf16).
__global__ void k_agg(const ushort* __restrict__ x) {
  int lane = threadIdx.x & 63;
  int node = (blockIdx.x * blockDim.x + threadIdx.x) >> 6;
  int beg = g_offs[node], end = g_offs[node + 1];
  float a0 = 0.f, a1 = 0.f;
  int col = lane * 2;
  for (int c = beg; c < end; c += 64) {
    int cnt = end - c;
    if (cnt > 64) cnt = 64;
    int my = g_csr[c + (lane < cnt ? lane : cnt - 1)];
    if ((uint)my >= (uint)NN) my = 0;
    int cnt4 = cnt & ~3;
    int j = 0;
    for (; j < cnt4; j += 4) {
      int s0 = __shfl(my, j), s1 = __shfl(my, j + 1);
      int s2 = __shfl(my, j + 2), s3 = __shfl(my, j + 3);
      uint r0 = *(const uint*)(x + (size_t)s0 * DD + col);
      uint r1 = *(const uint*)(x + (size_t)s1 * DD + col);
      uint r2 = *(const uint*)(x + (size_t)s2 * DD + col);
      uint r3 = *(const uint*)(x + (size_t)s3 * DD + col);
      a0 += blo(r0) + blo(r1) + blo(r2) + blo(r3);
      a1 += bhi(r0) + bhi(r1) + bhi(r2) + bhi(r3);
    }
    for (; j < cnt; ++j) {
      int s = __shfl(my, j);
      uint r = *(const uint*)(x + (size_t)s * DD + col);
      a0 += blo(r);
      a1 += bhi(r);
    }
  }
  int deg = end - beg;
  float inv = deg > 0 ? 1.0f / (float)deg : 0.f;
  a0 *= inv;
  a1 *= inv;
  ushort h0 = f2b(a0), h1 = f2b(a1);
  ushort l0 = f2b(a0 - b2f(h0)), l1 = f2b(a1 - b2f(h1));
  size_t o = (size_t)node * DD + col;
  *(uint*)(g_agg_h + o) = (uint)h0 | ((uint)h1 << 16);
  *(uint*)(g_agg_l + o) = (uint)l0 | ((uint)l1 << 16);
}

// ------- MFMA linear, bf16x3: out = act(A1@Wl^T + b + A2@Wr^T) -----------
// (ah+al)(bh+bl) ~= ah*bh + ah*bl + al*bh  (error ~2^-16 rel, fp32 accum)
// One wave = 32 rows (two 16-row tiles sharing every B fragment) x 128 cols.
// Loop nest ks-outer / nt-inner keeps live regs = {acc 64, A-slice 32, B 16}
// so the compiler can pipeline loads under MFMAs (old M=16 version sat at
// VGPR=68 with serialized per-nt B loads: 122us, MfmaUtil 6%).
// A frag: row=lane&15, k=(lane>>4)*8+j.  B frag: W row n=lane&15, same k.
// C/D: col=lane&15, row=(lane>>4)*4+reg.   (layouts verified: r4===r5 bitwise)
// MODE 0: bias+ReLU -> h hi/lo bf16.  MODE 1: bias+L2-normalize -> fp32 out.

#define MFMA16(a, b, c) __builtin_amdgcn_mfma_f32_16x16x32_bf16(a, b, c, 0, 0, 0)

template <int MODE>
__global__ __launch_bounds__(256, 3) void k_lin(
    const ushort* __restrict__ A1h, const ushort* __restrict__ A1l,
    const ushort* __restrict__ A2h, const ushort* __restrict__ A2l,
    const ushort* __restrict__ Wlh, const ushort* __restrict__ Wll,
    const ushort* __restrict__ Wrh, const ushort* __restrict__ Wrl,
    const float* __restrict__ bias, void* out0, ushort* __restrict__ outlo) {
  int lane = threadIdx.x & 63;
  int wid = threadIdx.x >> 6;
  int m = lane & 15, q = lane >> 4;
  int row0 = (blockIdx.x * 4 + wid) * 32;
  if (row0 >= NN) return;
  v4f acc[2][8];
#pragma unroll
  for (int t = 0; t < 2; t++)
#pragma unroll
    for (int nt = 0; nt < 8; nt++) acc[t][nt] = (v4f){0.f, 0.f, 0.f, 0.f};
  size_t aoff0 = (size_t)(row0 + m) * DD + q * 8;
  size_t aoff1 = aoff0 + (size_t)16 * DD;
#pragma unroll
  for (int ks = 0; ks < 4; ks++) {
    v8b a1h0 = *(const v8b*)(A1h + aoff0 + ks * 32);
    v8b a1l0 = *(const v8b*)(A1l + aoff0 + ks * 32);
    v8b a2h0 = *(const v8b*)(A2h + aoff0 + ks * 32);
    v8b a2l0 = *(const v8b*)(A2l + aoff0 + ks * 32);
    v8b a1h1 = *(const v8b*)(A1h + aoff1 + ks * 32);
    v8b a1l1 = *(const v8b*)(A1l + aoff1 + ks * 32);
    v8b a2h1 = *(const v8b*)(A2h + aoff1 + ks * 32);
    v8b a2l1 = *(const v8b*)(A2l + aoff1 + ks * 32);
#pragma unroll
    for (int nt = 0; nt < 8; nt++) {
      size_t boff = (size_t)(nt * 16 + m) * DD + q * 8 + ks * 32;
      v8b blh = *(const v8b*)(Wlh + boff);
      v8b bll = *(const v8b*)(Wll + boff);
      v8b brh = *(const v8b*)(Wrh + boff);
      v8b brl = *(const v8b*)(Wrl + boff);
      acc[0][nt] = MFMA16(a1h0, blh, acc[0][nt]);
      acc[0][nt] = MFMA16(a1h0, bll, acc[0][nt]);
      acc[0][nt] = MFMA16(a1l0, blh, acc[0][nt]);
      acc[0][nt] = MFMA16(a2h0, brh, acc[0][nt]);
      acc[0][nt] = MFMA16(a2h0, brl, acc[0][nt]);
      acc[0][nt] = MFMA16(a2l0, brh, acc[0][nt]);
      acc[1][nt] = MFMA16(a1h1, blh, acc[1][nt]);
      acc[1][nt] = MFMA16(a1h1, bll, acc[1][nt]);
      acc[1][nt] = MFMA16(a1l1, blh, acc[1][nt]);
      acc[1][nt] = MFMA16(a2h1, brh, acc[1][nt]);
      acc[1][nt] = MFMA16(a2h1, brl, acc[1][nt]);
      acc[1][nt] = MFMA16(a2l1, brh, acc[1][nt]);
    }
  }
  if (MODE == 0) {
    ushort* oh = (ushort*)out0;
#pragma unroll
    for (int t = 0; t < 2; t++) {
#pragma unroll
      for (int nt = 0; nt < 8; nt++) {
        float bv = bias[nt * 16 + m];
#pragma unroll
        for (int r = 0; r < 4; r++) {
          float v = acc[t][nt][r] + bv;
          v = v > 0.f ? v : 0.f;
          ushort hi = f2b(v);
          ushort lo = f2b(v - b2f(hi));
          size_t o = (size_t)(row0 + t * 16 + q * 4 + r) * DD + nt * 16 + m;
          oh[o] = hi;
          outlo[o] = lo;
        }
      }
    }
  } else {
    float* of = (float*)out0;
#pragma unroll
    for (int t = 0; t < 2; t++) {
#pragma unroll
      for (int r = 0; r < 4; r++) {
        float p = 0.f;
#pragma unroll
        for (int nt = 0; nt < 8; nt++) {
          float v = acc[t][nt][r] + bias[nt * 16 + m];
          acc[t][nt][r] = v;
          p += v * v;
        }
        p += __shfl_xor(p, 1);
        p += __shfl_xor(p, 2);
        p += __shfl_xor(p, 4);
        p += __shfl_xor(p, 8);
        float inv = (p > 0.f) ? 1.0f / fmaxf(sqrtf(p), 1e-12f) : 0.f;
#pragma unroll
        for (int nt = 0; nt < 8; nt++)
          of[(size_t)(row0 + t * 16 + q * 4 + r) * DD + nt * 16 + m] =
              acc[t][nt][r] * inv;
      }
    }
  }
}

// ---------------- launch ----------------

extern "C" void kernel_launch(void* const* d_in, const int* in_sizes, int n_in,
                              void* d_out, int out_size, void* d_ws, size_t ws_size,
                              hipStream_t stream) {
  const int* ei = (const int*)d_in[0];
  (void)in_sizes; (void)n_in; (void)out_size; (void)d_ws; (void)ws_size;

  ushort* wh;  hipGetSymbolAddress((void**)&wh, HIP_SYMBOL(g_w_h));
  ushort* wl;  hipGetSymbolAddress((void**)&wl, HIP_SYMBOL(g_w_l));
  ushort* wl0h = wh, *wr0h = wh + DD * DD, *wl1h = wh + 2 * DD * DD, *wr1h = wh + 3 * DD * DD;
  ushort* wl0l = wl, *wr0l = wl + DD * DD, *wl1l = wl + 2 * DD * DD, *wr1l = wl + 3 * DD * DD;
  float* bf;   hipGetSymbolAddress((void**)&bf, HIP_SYMBOL(g_biasf));
  float* b0 = bf, *b1 = bf + DD;
  ushort* eh;  hipGetSymbolAddress((void**)&eh, HIP_SYMBOL(g_emb_h));
  ushort* el;  hipGetSymbolAddress((void**)&el, HIP_SYMBOL(g_emb_l));
  ushort* ah;  hipGetSymbolAddress((void**)&ah, HIP_SYMBOL(g_agg_h));
  ushort* al;  hipGetSymbolAddress((void**)&al, HIP_SYMBOL(g_agg_l));
  ushort* hh;  hipGetSymbolAddress((void**)&hh, HIP_SYMBOL(g_hh));
  ushort* hl;  hipGetSymbolAddress((void**)&hl, HIP_SYMBOL(g_hl));

  k_detect_ei<<<1, 256, 0, stream>>>(ei);
  k_detect_f<<<1, 256, 0, stream>>>((const ushort*)d_in[1]);

  k_split<<<(NN * DD / 4 + 255) / 256, 256, 0, stream>>>(d_in[1], eh, el, NN * DD);
  k_split<<<(DD * DD / 4 + 255) / 256, 256, 0, stream>>>(d_in[2], wl0h, wl0l, DD * DD);
  k_split<<<(DD * DD / 4 + 255) / 256, 256, 0, stream>>>(d_in[4], wr0h, wr0l, DD * DD);
  k_split<<<(DD * DD / 4 + 255) / 256, 256, 0, stream>>>(d_in[5], wl1h, wl1l, DD * DD);
  k_split<<<(DD * DD / 4 + 255) / 256, 256, 0, stream>>>(d_in[7], wr1h, wr1l, DD * DD);
  k_cvtb<<<1, 128, 0, stream>>>(d_in[3], b0, DD);
  k_cvtb<<<1, 128, 0, stream>>>(d_in[6], b1, DD);

  k_zero2<<<1, 512, 0, stream>>>();
  k_bucket<<<NBLK1, 256, 0, stream>>>(ei);
  k_bscan<<<1, 512, 0, stream>>>();
  k_place<<<NB, 256, 0, stream>>>();

  k_agg<<<NN / 4, 256, 0, stream>>>(eh);
  k_lin<0><<<LGRID, 256, 0, stream>>>(ah, al, eh, el, wl0h, wl0l, wr0h, wr0l, b0, hh, hl);
  k_agg<<<NN / 4, 256, 0, stream>>>(hh);
  k_lin<1><<<LGRID, 256, 0, stream>>>(ah, al, hh, hl, wl1h, wl1l, wr1h, wr1l, b1, d_out, nullptr);
}